// Round 1
// baseline (425.130 us; speedup 1.0000x reference)
//
#include <hip/hip_runtime.h>

#define BDIM 256

// out[b,co,p,q] (NCHW) = (z + b2)*m0, where z is conv_transpose(conv1-masked).
// Collapsed form per m0-active pixel (p,q):
//   z[co] = sum_{valid taps (di,dj)} sum_{ei,ej} x[p-2+di+ei, q-2+dj+ej] * M[di,dj,ei,ej,co]
//         + Btab[case(p)][case(q)][co]
//   M[tap,e,co]   = sum_ci W1[e,ci] * W2[tap,ci,co]
//   Btab[a][b][co]= b2[co] + sum_{taps valid for case (a,b)} sum_ci b1[ci]*W2[tap,ci,co]
// Inactive pixels: out = 0.
__global__ __launch_bounds__(BDIM) void net_kernel(
    const float* __restrict__ x,    // [B,64,64,1]
    const float* __restrict__ W1,   // [3,3,1,64]
    const float* __restrict__ b1,   // [64]
    const float* __restrict__ W2,   // [3,3,64,32]
    const float* __restrict__ b2,   // [32]
    float* __restrict__ out)        // [B,32,64,64]
{
  const int b    = blockIdx.x;
  const int tid  = threadIdx.x;
  const int lane = tid & 63;
  const int wave = tid >> 6;

  __shared__ __align__(16) float W1L[576];        // [e][ci]
  __shared__ __align__(16) float Mlds[9 * 9 * 32]; // [tap][e][co]
  __shared__ __align__(16) float BvL[9 * 32];      // [tap][co]
  __shared__ __align__(16) float Btab[25 * 32];    // [case_p*5+case_q][co]
  __shared__ __align__(16) float xp[68 * 68];      // zero-padded x tile
  __shared__ unsigned long long Rm[64];            // per-row activity bitmask
  __shared__ unsigned short alist[4096];           // active (p<<6|q)
  __shared__ int nact_sh;

  // ---- stage W1 ----
  for (int i = tid; i < 576; i += BDIM) W1L[i] = W1[i];
  __syncthreads();

  // ---- build M[tap][e][co] and Bv[tap][co] (each W2 element read once) ----
  {
    const int co = tid & 31;
    for (int tap = tid >> 5; tap < 9; tap += 8) {
      float acc[9] = {0.f, 0.f, 0.f, 0.f, 0.f, 0.f, 0.f, 0.f, 0.f};
      float accB = 0.f;
      for (int ci = 0; ci < 64; ++ci) {
        float w2 = W2[(tap * 64 + ci) * 32 + co];
        accB = fmaf(b1[ci], w2, accB);
#pragma unroll
        for (int e = 0; e < 9; ++e) acc[e] = fmaf(W1L[e * 64 + ci], w2, acc[e]);
      }
#pragma unroll
      for (int e = 0; e < 9; ++e) Mlds[(tap * 9 + e) * 32 + co] = acc[e];
      BvL[tap * 32 + co] = accB;
    }
  }
  __syncthreads();

  // ---- Btab: bias sums per border-case (valid-tap sets) ----
  for (int t = tid; t < 800; t += BDIM) {
    const int dmask[5] = {4, 6, 7, 3, 1};  // p=0:{2} p=1:{1,2} int:{0,1,2} 62:{0,1} 63:{0}
    int co = t & 31;
    int ab = t >> 5;
    int a = ab / 5, c = ab % 5;
    float s = b2[co];
    for (int di = 0; di < 3; ++di)
      if ((dmask[a] >> di) & 1)
        for (int dj = 0; dj < 3; ++dj)
          if ((dmask[c] >> dj) & 1) s += BvL[(di * 3 + dj) * 32 + co];
    Btab[t] = s;
  }
  // ---- zero the padded x tile ----
  for (int i = tid; i < 68 * 68; i += BDIM) xp[i] = 0.f;
  __syncthreads();

  // ---- load x interior (float4 global, float2 LDS writes for alignment) ----
  const float* xb = x + (size_t)b * 4096;
  for (int i = tid; i < 1024; i += BDIM) {
    float4 v = reinterpret_cast<const float4*>(xb)[i];
    int r = i >> 4;
    int c4 = (i & 15) << 2;
    float2* d2 = reinterpret_cast<float2*>(&xp[(2 + r) * 68 + 2 + c4]);
    d2[0] = make_float2(v.x, v.y);
    d2[1] = make_float2(v.z, v.w);
  }
  __syncthreads();

  // ---- per-row activity masks via 64-lane ballot ----
  for (int r = wave; r < 64; r += 4) {
    int pred = (xp[(2 + r) * 68 + 2 + lane] != 0.0f);
    unsigned long long m = __ballot(pred);
    if (lane == 0) Rm[r] = m;
  }
  __syncthreads();

  // ---- active-pixel list (wave 0: one lane per row, prefix scan) ----
  if (wave == 0) {
    unsigned long long m = Rm[lane];
    int cnt = __popcll(m);
    int incl = cnt;
#pragma unroll
    for (int s = 1; s < 64; s <<= 1) {
      int v = __shfl_up(incl, s);
      if (lane >= s) incl += v;
    }
    int ofs = incl - cnt;
    unsigned long long mm = m;
    while (mm) {
      int q = __builtin_ctzll(mm);
      alist[ofs++] = (unsigned short)((lane << 6) | q);
      mm &= mm - 1;
    }
    if (lane == 63) nact_sh = incl;
  }
  __syncthreads();

  const int nact = nact_sh;
  float* outb = out + (size_t)b * (32 * 4096);

  // ---- compute active pixels: 32 channels each ----
  for (int n = tid; n < nact; n += BDIM) {
    int pq = alist[n];
    int p = pq >> 6, q = pq & 63;
    int cp = ((unsigned)(p - 2) < 60u) ? 2 : (p < 2 ? p : p - 59);
    int cq = ((unsigned)(q - 2) < 60u) ? 2 : (q < 2 ? q : q - 59);
    float4 z[8];
    const float4* bt = reinterpret_cast<const float4*>(&Btab[(cp * 5 + cq) * 32]);
#pragma unroll
    for (int k = 0; k < 8; ++k) z[k] = bt[k];

    for (int di = 0; di < 3; ++di) {
      if ((unsigned)(p - 2 + di) >= 62u) continue;  // tap row out of y-range
      for (int dj = 0; dj < 3; ++dj) {
        if ((unsigned)(q - 2 + dj) >= 62u) continue;
        const float4* Mt =
            reinterpret_cast<const float4*>(&Mlds[(di * 3 + dj) * 288]);
#pragma unroll
        for (int ei = 0; ei < 3; ++ei) {
#pragma unroll
          for (int ej = 0; ej < 3; ++ej) {
            float xv = xp[(p + di + ei) * 68 + (q + dj + ej)];
            const float4* Me = Mt + (ei * 3 + ej) * 8;
#pragma unroll
            for (int k = 0; k < 8; ++k) {
              float4 mv = Me[k];
              z[k].x = fmaf(xv, mv.x, z[k].x);
              z[k].y = fmaf(xv, mv.y, z[k].y);
              z[k].z = fmaf(xv, mv.z, z[k].z);
              z[k].w = fmaf(xv, mv.w, z[k].w);
            }
          }
        }
      }
    }
    int base = (p << 6) | q;
#pragma unroll
    for (int k = 0; k < 8; ++k) {
      outb[((4 * k + 0) << 12) + base] = z[k].x;
      outb[((4 * k + 1) << 12) + base] = z[k].y;
      outb[((4 * k + 2) << 12) + base] = z[k].z;
      outb[((4 * k + 3) << 12) + base] = z[k].w;
    }
  }

  // ---- dense zero-fill of inactive elements (disjoint from active stores) ----
  for (int s = tid; s < 32 * 1024; s += BDIM) {
    int co = s >> 10;
    int pq4 = s & 1023;
    int p = pq4 >> 4;
    int q0 = (pq4 & 15) << 2;
    unsigned bits = (unsigned)(Rm[p] >> q0) & 0xFu;
    float* dst = outb + (co << 12) + (p << 6) + q0;
    if (bits == 0u) {
      *reinterpret_cast<float4*>(dst) = make_float4(0.f, 0.f, 0.f, 0.f);
    } else {
      if (!(bits & 1u)) dst[0] = 0.f;
      if (!(bits & 2u)) dst[1] = 0.f;
      if (!(bits & 4u)) dst[2] = 0.f;
      if (!(bits & 8u)) dst[3] = 0.f;
    }
  }
}

extern "C" void kernel_launch(void* const* d_in, const int* in_sizes, int n_in,
                              void* d_out, int out_size, void* d_ws, size_t ws_size,
                              hipStream_t stream) {
  const float* x  = (const float*)d_in[0];
  const float* W1 = (const float*)d_in[1];
  const float* b1 = (const float*)d_in[2];
  const float* W2 = (const float*)d_in[3];
  const float* b2 = (const float*)d_in[4];
  float* out = (float*)d_out;
  int B = in_sizes[0] / 4096;  // 1024 images of 64*64*1
  hipLaunchKernelGGL(net_kernel, dim3(B), dim3(BDIM), 0, stream,
                     x, W1, b1, W2, b2, out);
}

// Round 2
// 397.158 us; speedup vs baseline: 1.0704x; 1.0704x over previous
//
#include <hip/hip_runtime.h>

#define BDIM 256
#define BTAB_OFF 20000  // floats: Kc occupies [0,20000), Btab [20000,20800)

// case index along one axis: 0 (p==0), 1 (p==1), 2 (interior), 3 (p==62), 4 (p==63)
__device__ __forceinline__ int casef(int p) {
  return ((unsigned)(p - 2) < 60u) ? 2 : (p < 2 ? p : p - 59);
}

// ---------------- prep: build collapsed 5x5 kernels per border-case ----------------
// Kc[(a*5+c)][u*5+v][co] = sum over taps (di in D[a], dj in D[c]) with e=(u-di,v-dj) in [0,3)^2
//                          of M[di,dj,e,co],   M[tap,e,co] = sum_ci W1[e,ci]*W2[tap,ci,co]
// Btab[(a*5+c)][co] = b2[co] + sum_{valid taps} sum_ci b1[ci]*W2[tap,ci,co]
__global__ __launch_bounds__(BDIM) void prep_kernel(
    const float* __restrict__ W1, const float* __restrict__ b1,
    const float* __restrict__ W2, const float* __restrict__ b2,
    float* __restrict__ ws) {
  __shared__ float Mlds[9 * 9 * 32];
  __shared__ float BvL[9 * 32];
  const int tid = threadIdx.x;
  const int co = tid & 31;
  for (int tap = tid >> 5; tap < 9; tap += 8) {
    float acc[9] = {0.f, 0.f, 0.f, 0.f, 0.f, 0.f, 0.f, 0.f, 0.f};
    float accB = 0.f;
    for (int ci = 0; ci < 64; ++ci) {
      float w2 = W2[(tap * 64 + ci) * 32 + co];
      accB = fmaf(b1[ci], w2, accB);
#pragma unroll
      for (int e = 0; e < 9; ++e) acc[e] = fmaf(W1[e * 64 + ci], w2, acc[e]);
    }
#pragma unroll
    for (int e = 0; e < 9; ++e) Mlds[(tap * 9 + e) * 32 + co] = acc[e];
    BvL[tap * 32 + co] = accB;
  }
  __syncthreads();

  const int a = blockIdx.x / 5, c = blockIdx.x % 5;
  const int dmask[5] = {4, 6, 7, 3, 1};
  const int Da = dmask[a], Dc = dmask[c];
  for (int t = tid; t < 800; t += BDIM) {
    int uv = t >> 5, cc = t & 31;
    int u = uv / 5, v = uv % 5;
    float s = 0.f;
    for (int di = 0; di < 3; ++di) {
      if (!((Da >> di) & 1)) continue;
      int ei = u - di;
      if ((unsigned)ei > 2u) continue;
      for (int dj = 0; dj < 3; ++dj) {
        if (!((Dc >> dj) & 1)) continue;
        int ej = v - dj;
        if ((unsigned)ej > 2u) continue;
        s += Mlds[((di * 3 + dj) * 9 + ei * 3 + ej) * 32 + cc];
      }
    }
    ws[(a * 5 + c) * 800 + uv * 32 + cc] = s;
  }
  if (tid < 32) {
    float s = b2[tid];
    for (int di = 0; di < 3; ++di)
      if ((Da >> di) & 1)
        for (int dj = 0; dj < 3; ++dj)
          if ((Dc >> dj) & 1) s += BvL[(di * 3 + dj) * 32 + tid];
    ws[BTAB_OFF + (a * 5 + c) * 32 + tid] = s;
  }
}

// ---------------- main: per 32-row half-image, quad-list compute + zero fill ----------------
__global__ __launch_bounds__(BDIM) void main_kernel(
    const float* __restrict__ x, const float* __restrict__ ws,
    float* __restrict__ out) {
  const int bb = blockIdx.x;
  const int b = bb >> 1;
  const int r0 = (bb & 1) << 5;  // 0 or 32
  const int tid = threadIdx.x;
  const int lane = tid & 63;
  const int wave = tid >> 6;

  __shared__ __align__(16) float xp[36 * 68];  // x rows r0-2 .. r0+33, cols -2..65
  __shared__ unsigned long long Rm[32];        // activity mask per own row
  __shared__ unsigned short aq[512];           // active quads (>=1 active pixel)
  __shared__ int nq_sh;

  if (tid == 0) nq_sh = 0;
  float4* xp4 = reinterpret_cast<float4*>(xp);
  for (int i = tid; i < 612; i += BDIM) xp4[i] = make_float4(0.f, 0.f, 0.f, 0.f);
  __syncthreads();

  const float* xb = x + (size_t)b * 4096;
  for (int it = tid; it < 576; it += BDIM) {
    int i = it >> 4, c4 = (it & 15) << 2;
    int r = r0 - 2 + i;
    if ((unsigned)r < 64u) {
      float4 v = *reinterpret_cast<const float4*>(xb + r * 64 + c4);
      float2* d2 = reinterpret_cast<float2*>(&xp[i * 68 + 2 + c4]);
      d2[0] = make_float2(v.x, v.y);
      d2[1] = make_float2(v.z, v.w);
    }
  }
  __syncthreads();

  for (int k = wave; k < 32; k += 4) {
    int pred = (xp[(k + 2) * 68 + 2 + lane] != 0.0f);
    unsigned long long m = __ballot(pred);
    if (lane == 0) Rm[k] = m;
  }
  __syncthreads();

  for (int g = tid; g < 512; g += BDIM) {
    unsigned bits = (unsigned)(Rm[g >> 4] >> ((g & 15) << 2)) & 0xFu;
    if (bits) {
      int idx = atomicAdd(&nq_sh, 1);
      aq[idx] = (unsigned short)g;
    }
  }
  __syncthreads();

  const int nq = nq_sh;
  const float* Kc = ws;
  const float* Btab = ws + BTAB_OFF;
  float* outb = out + (size_t)b * (32 * 4096);

  // compute pass: item = (active quad, co) -> one float4 of 4 pixels, 1 channel
  const int nitems = nq << 5;
  for (int n = tid; n < nitems; n += BDIM) {
    int g = aq[n >> 5];
    int co = n & 31;
    int k = g >> 4, q0 = (g & 15) << 2;
    int p = r0 + k;
    unsigned bits = (unsigned)(Rm[k] >> q0) & 0xFu;
    int cp = casef(p);
    float z0, z1, z2, z3;
    if ((unsigned)(q0 - 4) <= 52u) {  // q0 in [4,56]: all 4 pixels are q-interior
      const float* Kp = Kc + (cp * 5 + 2) * 800 + co;
      float bias = Btab[(cp * 5 + 2) * 32 + co];
      z0 = z1 = z2 = z3 = bias;
#pragma unroll
      for (int u = 0; u < 5; ++u) {
        const float* xr = &xp[(k + u) * 68 + q0];
        float4 xa = *reinterpret_cast<const float4*>(xr);
        float4 xc = *reinterpret_cast<const float4*>(xr + 4);
        float xv[8] = {xa.x, xa.y, xa.z, xa.w, xc.x, xc.y, xc.z, xc.w};
#pragma unroll
        for (int v = 0; v < 5; ++v) {
          float Kv = Kp[(u * 5 + v) << 5];
          z0 = fmaf(xv[v], Kv, z0);
          z1 = fmaf(xv[v + 1], Kv, z1);
          z2 = fmaf(xv[v + 2], Kv, z2);
          z3 = fmaf(xv[v + 3], Kv, z3);
        }
      }
    } else {  // q-border quad: per-pixel case
      int c0 = casef(q0), c1 = casef(q0 + 1), c2 = casef(q0 + 2), c3 = casef(q0 + 3);
      const float* K0 = Kc + (cp * 5 + c0) * 800 + co;
      const float* K1 = Kc + (cp * 5 + c1) * 800 + co;
      const float* K2 = Kc + (cp * 5 + c2) * 800 + co;
      const float* K3 = Kc + (cp * 5 + c3) * 800 + co;
      z0 = Btab[(cp * 5 + c0) * 32 + co];
      z1 = Btab[(cp * 5 + c1) * 32 + co];
      z2 = Btab[(cp * 5 + c2) * 32 + co];
      z3 = Btab[(cp * 5 + c3) * 32 + co];
#pragma unroll
      for (int u = 0; u < 5; ++u) {
        const float* xr = &xp[(k + u) * 68 + q0];
        float4 xa = *reinterpret_cast<const float4*>(xr);
        float4 xc = *reinterpret_cast<const float4*>(xr + 4);
        float xv[8] = {xa.x, xa.y, xa.z, xa.w, xc.x, xc.y, xc.z, xc.w};
#pragma unroll
        for (int v = 0; v < 5; ++v) {
          int o = (u * 5 + v) << 5;
          z0 = fmaf(xv[v], K0[o], z0);
          z1 = fmaf(xv[v + 1], K1[o], z1);
          z2 = fmaf(xv[v + 2], K2[o], z2);
          z3 = fmaf(xv[v + 3], K3[o], z3);
        }
      }
    }
    if (!(bits & 1u)) z0 = 0.f;
    if (!(bits & 2u)) z1 = 0.f;
    if (!(bits & 4u)) z2 = 0.f;
    if (!(bits & 8u)) z3 = 0.f;
    *reinterpret_cast<float4*>(outb + (((size_t)co) << 12) + (p << 6) + q0) =
        make_float4(z0, z1, z2, z3);
  }

  // fill pass: zero float4 at every inactive quad, all channels
  for (int s = tid; s < 512 * 32; s += BDIM) {
    int co = s >> 9, g = s & 511;
    unsigned bits = (unsigned)(Rm[g >> 4] >> ((g & 15) << 2)) & 0xFu;
    if (bits) continue;
    int p = r0 + (g >> 4), q0 = (g & 15) << 2;
    *reinterpret_cast<float4*>(outb + (((size_t)co) << 12) + (p << 6) + q0) =
        make_float4(0.f, 0.f, 0.f, 0.f);
  }
}

extern "C" void kernel_launch(void* const* d_in, const int* in_sizes, int n_in,
                              void* d_out, int out_size, void* d_ws, size_t ws_size,
                              hipStream_t stream) {
  const float* x  = (const float*)d_in[0];
  const float* W1 = (const float*)d_in[1];
  const float* b1 = (const float*)d_in[2];
  const float* W2 = (const float*)d_in[3];
  const float* b2 = (const float*)d_in[4];
  float* out = (float*)d_out;
  float* ws  = (float*)d_ws;
  int B = in_sizes[0] / 4096;  // 1024 images of 64x64x1

  hipLaunchKernelGGL(prep_kernel, dim3(25), dim3(BDIM), 0, stream, W1, b1, W2, b2, ws);
  hipLaunchKernelGGL(main_kernel, dim3(2 * B), dim3(BDIM), 0, stream, x, ws, out);
}